// Round 11
// baseline (460.574 us; speedup 1.0000x reference)
//
#include <hip/hip_runtime.h>
#include <hip/hip_bf16.h>

// PointSelfAttention R11 (= R9 dataflow + k_fused LDS diet -> 2 blocks/CU):
//   k_prep_w  : w_qkv -> bf16 [col][K] PRE-SWIZZLED; w_out -> bf16 [col][K] plain
//   k_prep_tbl: per-head RBF bias table (512 entries, stays in global/L2)
//   k_prep_h  : h fp32 -> bf16, pre-swizzled, per half
//   k_qkv     : m97-style GEMM 128x256 tile BK=64, global_load_lds, 48KB LDS
//   k_fused   : per molecule (8 waves = 8 heads), R9 dataflow; dist-cache as ushort
//               fixed-point, bias table read from L2 -> 77.5KB LDS, 2 blocks/CU.

#define HID 512
#define TBL 512
#define DMAX 12.0f

typedef __attribute__((ext_vector_type(4))) float f32x4;
typedef __attribute__((ext_vector_type(8))) short bhalf8;

__device__ __forceinline__ short f2bf(float f) {
    union { float f; unsigned u; } x; x.f = f;
    unsigned u = x.u;
    unsigned r = (u + 0x7FFFu + ((u >> 16) & 1u)) >> 16;  // RNE
    return (short)r;
}

__device__ __forceinline__ void gld_lds16(const void* g, void* l) {
    __builtin_amdgcn_global_load_lds((const __attribute__((address_space(1))) void*)g,
                                     (__attribute__((address_space(3))) void*)l, 16, 0, 0);
}

// ---- prep: transpose weights to bf16 [cols][K]; wqT pre-swizzled ----
__global__ __launch_bounds__(256) void k_prep_w(const float* __restrict__ w_qkv,
                                                const float* __restrict__ w_out,
                                                short* __restrict__ wqT,
                                                short* __restrict__ woT) {
    __shared__ short tile[64][68];
    const int t = threadIdx.x;
    int bt = blockIdx.x;
    const float* src; short* dst; int sld, tk, tc, swz;
    if (bt < 192) { src = w_qkv; dst = wqT; sld = 1536; tk = bt & 7; tc = bt >> 3; swz = 1; }
    else { int b2 = bt - 192; src = w_out; dst = woT; sld = 512; tk = b2 & 7; tc = b2 >> 3; swz = 0; }
#pragma unroll
    for (int p = 0; p < 4; ++p) {
        int s = t + 256 * p;
        int r = s >> 4, sg = s & 15;
        const float4 v = *(const float4*)(src + (tk * 64 + r) * sld + tc * 64 + sg * 4);
        tile[r][sg * 4 + 0] = f2bf(v.x);
        tile[r][sg * 4 + 1] = f2bf(v.y);
        tile[r][sg * 4 + 2] = f2bf(v.z);
        tile[r][sg * 4 + 3] = f2bf(v.w);
    }
    __syncthreads();
#pragma unroll
    for (int p = 0; p < 16; ++p) {
        int o = t + 256 * p;
        int c = o >> 6, k = o & 63;
        int kk = swz ? (k ^ ((c & 7) << 3)) : k;
        dst[(tc * 64 + c) * 512 + tk * 64 + kk] = tile[k][c];
    }
}

// ---- prep: per-head bias(d) table [8][512] ----
__global__ __launch_bounds__(256) void k_prep_tbl(const float* __restrict__ centers,
                                                  const float* __restrict__ w_rbf,
                                                  const float* __restrict__ b_rbf,
                                                  float* __restrict__ tbl) {
    int idx = blockIdx.x * 256 + threadIdx.x;   // 8 heads * 512
    int hh = idx >> 9, i = idx & (TBL - 1);
    float d = (float)i * (DMAX / (float)(TBL - 1));
    float s = b_rbf[hh];
    const float invw = 1.0f / 0.0625f;          // width = (8/32)^2
#pragma unroll 4
    for (int r = 0; r < 32; ++r) {
        float tt = d - centers[r];
        s += w_rbf[r * 8 + hh] * expf(-(tt * tt) * invw);
    }
    tbl[idx] = s;
}

// ---- prep: h (fp32) -> bf16 pre-swizzled, one half (32768 rows) ----
__global__ __launch_bounds__(256) void k_prep_h(const float* __restrict__ h,
                                                short* __restrict__ hbf,
                                                int molbase) {
    size_t i = ((size_t)blockIdx.x * 256 + threadIdx.x) * 8;   // short idx within half
    const float* src = h + (size_t)molbase * 64 * HID + i;
    float4 a = *(const float4*)src;
    float4 b = *(const float4*)(src + 4);
    short s8[8];
    s8[0] = f2bf(a.x); s8[1] = f2bf(a.y); s8[2] = f2bf(a.z); s8[3] = f2bf(a.w);
    s8[4] = f2bf(b.x); s8[5] = f2bf(b.y); s8[6] = f2bf(b.z); s8[7] = f2bf(b.w);
    int row = (int)(i >> 9);
    size_t o = i ^ (size_t)((row & 7) << 3);   // swizzle 16B slots within 64-short chunk
    *(int4*)(hbf + o) = *(int4*)s8;
}

// ---- QKV GEMM (m97-style): 128x256 tile, BK=64, global_load_lds, 1 buffer ----
__global__ __launch_bounds__(512) void k_qkv(const short* __restrict__ hbf,
                                             const float* __restrict__ b_qkv,
                                             const short* __restrict__ wqT,
                                             short* __restrict__ qkvb) {
    __shared__ __align__(16) short As[128 * 64];   // 16 KB
    __shared__ __align__(16) short Bs[256 * 64];   // 32 KB
    const int t = threadIdx.x;
    const int lane = t & 63, wave = t >> 6;
    const int l16 = lane & 15, g = lane >> 4;
    const int wrow = wave >> 2, wcol = wave & 3;   // 2 x 4 wave grid

    int wg = blockIdx.x;                           // 1536 wgs; XCD swizzle
    wg = (wg & 7) * 192 + (wg >> 3);
    const int bx = wg & 255, by = wg >> 8;
    const int R0l = bx * 128;
    const int C0 = by * 256;

    f32x4 acc[4][4];
#pragma unroll
    for (int i = 0; i < 4; ++i)
#pragma unroll
        for (int j = 0; j < 4; ++j) acc[i][j] = (f32x4){0.f, 0.f, 0.f, 0.f};

    const int lrow = lane >> 3, lslot = lane & 7;
    const int axor = (l16 & 7) << 3;

    for (int kc = 0; kc < 8; ++kc) {
        const int kb = kc * 64;
#pragma unroll
        for (int j = 0; j < 2; ++j) {
            int row = wave * 16 + j * 8 + lrow;
            gld_lds16(hbf + (size_t)(R0l + row) * HID + kb + lslot * 8,
                      (char*)As + wave * 2048 + j * 1024 + lane * 16);
        }
#pragma unroll
        for (int j = 0; j < 4; ++j) {
            int row = wave * 32 + j * 8 + lrow;
            gld_lds16(wqT + (size_t)(C0 + row) * HID + kb + lslot * 8,
                      (char*)Bs + wave * 4096 + j * 1024 + lane * 16);
        }
        __syncthreads();
#pragma unroll
        for (int kk = 0; kk < 2; ++kk) {
            const int cs = (kk * 32 + g * 8) ^ axor;
            bhalf8 af[4], bf[4];
#pragma unroll
            for (int mt = 0; mt < 4; ++mt)
                af[mt] = *(const bhalf8*)(&As[(wrow * 64 + mt * 16 + l16) * 64 + cs]);
#pragma unroll
            for (int nt = 0; nt < 4; ++nt)
                bf[nt] = *(const bhalf8*)(&Bs[(wcol * 64 + nt * 16 + l16) * 64 + cs]);
#pragma unroll
            for (int mt = 0; mt < 4; ++mt)
#pragma unroll
                for (int nt = 0; nt < 4; ++nt)
                    acc[mt][nt] = __builtin_amdgcn_mfma_f32_16x16x32_bf16(
                        af[mt], bf[nt], acc[mt][nt], 0, 0, 0);
        }
        __syncthreads();
    }

    const int sec = C0 >> 9;
    const float mul = (sec == 0) ? 0.125f : 1.0f;
#pragma unroll
    for (int nt = 0; nt < 4; ++nt) {
        int c = C0 + wcol * 64 + nt * 16 + l16;
        float bv = b_qkv[c];
        int head = (c >> 6) & 7, d = c & 63;
#pragma unroll
        for (int mt = 0; mt < 4; ++mt) {
            int rowl = R0l + wrow * 64 + mt * 16 + g * 4;
            int mol_local = rowl >> 6;
            int rloc = rowl & 63;
            short* panel = qkvb + (size_t)((mol_local * 3 + sec) * 8 + head) * 4096;
            if (sec == 2) {
                short4 s4;
                s4.x = f2bf(acc[mt][nt][0] + bv);
                s4.y = f2bf(acc[mt][nt][1] + bv);
                s4.z = f2bf(acc[mt][nt][2] + bv);
                s4.w = f2bf(acc[mt][nt][3] + bv);
                *(short4*)(panel + d * 64 + rloc) = s4;
            } else {
#pragma unroll
                for (int r = 0; r < 4; ++r)
                    panel[(rloc + r) * 64 + d] = f2bf((acc[mt][nt][r] + bv) * mul);
            }
        }
    }
}

// ---- fused attention + out-proj + residual + LayerNorm; 1 block = 1 molecule;
//      77.5 KB LDS -> 2 blocks/CU ----
__global__ __launch_bounds__(512, 4) void k_fused(const short* __restrict__ qkvb,
                                                  const float* __restrict__ pos,
                                                  const float* __restrict__ tbl,
                                                  const float* __restrict__ h,
                                                  const short* __restrict__ woT,
                                                  const float* __restrict__ b_out,
                                                  const float* __restrict__ gamma,
                                                  const float* __restrict__ beta,
                                                  float* __restrict__ out,
                                                  int molbase) {
    __shared__ __align__(16) short uP[8 * 4096];   // per-wave P[64][64] -> agg[64][512]
    __shared__ unsigned short s_dc[64 * 66];       // 8.4 KB dist-cache u*64 fixed-point
    __shared__ float s_px[64], s_py[64], s_pz[64];
    __shared__ float red[64 * 16];
    __shared__ float mr[64 * 2];

    const int t = threadIdx.x;
    const int wave = t >> 6, lane = t & 63;
    const int l16 = lane & 15, g = lane >> 4;
    const int mol_local = blockIdx.x;
    const int rowbase = (molbase + mol_local) * 64;
    const float tscale = (float)(TBL - 1) / DMAX;

    if (t < 64) {
        s_px[t] = pos[(rowbase + t) * 3 + 0];
        s_py[t] = pos[(rowbase + t) * 3 + 1];
        s_pz[t] = pos[(rowbase + t) * 3 + 2];
    }
    __syncthreads();

    // shared distance cache: u = min(dist,DMAX)*tscale, stored as ushort u*64
    {
        int row = t >> 3, c0 = (t & 7) * 8;
        float rx = s_px[row], ry = s_py[row], rz = s_pz[row];
#pragma unroll
        for (int j = 0; j < 8; ++j) {
            int col = c0 + j;
            float dx = rx - s_px[col], dy = ry - s_py[col], dz = rz - s_pz[col];
            float dd = fmaf(dx, dx, fmaf(dy, dy, dz * dz));
            float dist = sqrtf(fmaxf(dd, 1e-12f));
            float u = fminf(dist, DMAX) * tscale;
            s_dc[row * 66 + col] = (unsigned short)(u * 64.0f + 0.5f);
        }
    }
    __syncthreads();

    const short* qp = qkvb + ((size_t)(mol_local * 3 + 0) * 8 + wave) * 4096;
    const short* kp = qkvb + ((size_t)(mol_local * 3 + 1) * 8 + wave) * 4096;
    const short* vt = qkvb + ((size_t)(mol_local * 3 + 2) * 8 + wave) * 4096;  // [d][key]

    // ---- S = q_scaled . k^T (wave owns full 64x64 of its head) ----
    f32x4 sacc[4][4];
#pragma unroll
    for (int i = 0; i < 4; ++i)
#pragma unroll
        for (int j = 0; j < 4; ++j) sacc[i][j] = (f32x4){0.f, 0.f, 0.f, 0.f};
#pragma unroll
    for (int kk = 0; kk < 2; ++kk) {
        bhalf8 qa[4], kb[4];
#pragma unroll
        for (int mt = 0; mt < 4; ++mt)
            qa[mt] = *(const bhalf8*)(qp + (mt * 16 + l16) * 64 + kk * 32 + g * 8);
#pragma unroll
        for (int nt = 0; nt < 4; ++nt)
            kb[nt] = *(const bhalf8*)(kp + (nt * 16 + l16) * 64 + kk * 32 + g * 8);
#pragma unroll
        for (int mt = 0; mt < 4; ++mt)
#pragma unroll
            for (int nt = 0; nt < 4; ++nt)
                sacc[mt][nt] = __builtin_amdgcn_mfma_f32_16x16x32_bf16(
                    qa[mt], kb[nt], sacc[mt][nt], 0, 0, 0);
    }

    // ---- + RBF bias: ushort dist-cache + per-head table lerp (table from L2) ----
    const float* T = tbl + wave * TBL;
#pragma unroll
    for (int nt = 0; nt < 4; ++nt) {
        int col = nt * 16 + l16;
#pragma unroll
        for (int mt = 0; mt < 4; ++mt) {
#pragma unroll
            for (int r = 0; r < 4; ++r) {
                int row = mt * 16 + g * 4 + r;
                float u = (float)s_dc[row * 66 + col] * 0.015625f;
                int i = (int)u; if (i > TBL - 2) i = TBL - 2;
                float fr = u - (float)i;
                float t0 = T[i];
                sacc[mt][nt][r] += fmaf(fr, T[i + 1] - t0, t0);
            }
        }
    }

    // ---- softmax rows + P (XOR-swizzled 16-B groups) ----
    float inv[4][4];
    short* Pw = uP + wave * 4096;
#pragma unroll
    for (int mt = 0; mt < 4; ++mt) {
#pragma unroll
        for (int r = 0; r < 4; ++r) {
            float m = fmaxf(fmaxf(sacc[mt][0][r], sacc[mt][1][r]),
                            fmaxf(sacc[mt][2][r], sacc[mt][3][r]));
#pragma unroll
            for (int off = 1; off < 16; off <<= 1) m = fmaxf(m, __shfl_xor(m, off, 64));
            float e[4], ssum = 0.f;
#pragma unroll
            for (int nt = 0; nt < 4; ++nt) { e[nt] = __expf(sacc[mt][nt][r] - m); ssum += e[nt]; }
#pragma unroll
            for (int off = 1; off < 16; off <<= 1) ssum += __shfl_xor(ssum, off, 64);
            inv[mt][r] = 1.0f / ssum;
            int row = mt * 16 + g * 4 + r;
            int rho = row & 7;
#pragma unroll
            for (int nt = 0; nt < 4; ++nt) {
                int c = nt * 16 + l16;
                Pw[row * 64 + (((c >> 3) ^ rho) << 3) + (c & 7)] = f2bf(e[nt]);
            }
        }
    }

    // ---- PV: agg_head = P @ V  (V^T frags direct from global) ----
    f32x4 oacc[4][4];
#pragma unroll
    for (int i = 0; i < 4; ++i)
#pragma unroll
        for (int j = 0; j < 4; ++j) oacc[i][j] = (f32x4){0.f, 0.f, 0.f, 0.f};
#pragma unroll
    for (int kk = 0; kk < 2; ++kk) {
        bhalf8 pa[4], vb[4];
#pragma unroll
        for (int mt = 0; mt < 4; ++mt)
            pa[mt] = *(const bhalf8*)(Pw + (mt * 16 + l16) * 64 +
                                      (((kk * 4 + g) ^ (l16 & 7)) << 3));
#pragma unroll
        for (int nt = 0; nt < 4; ++nt)
            vb[nt] = *(const bhalf8*)(vt + (nt * 16 + l16) * 64 + kk * 32 + g * 8);
#pragma unroll
        for (int mt = 0; mt < 4; ++mt)
#pragma unroll
            for (int nt = 0; nt < 4; ++nt)
                oacc[mt][nt] = __builtin_amdgcn_mfma_f32_16x16x32_bf16(
                    pa[mt], vb[nt], oacc[mt][nt], 0, 0, 0);
    }
#pragma unroll
    for (int mt = 0; mt < 4; ++mt)
#pragma unroll
        for (int nt = 0; nt < 4; ++nt)
#pragma unroll
            for (int r = 0; r < 4; ++r) oacc[mt][nt][r] *= inv[mt][r];

    __syncthreads();   // all waves done reading P; uP becomes agg[64][512]

#pragma unroll
    for (int mt = 0; mt < 4; ++mt) {
#pragma unroll
        for (int r = 0; r < 4; ++r) {
            int row = mt * 16 + g * 4 + r;
            int rho = row & 7;
#pragma unroll
            for (int nt = 0; nt < 4; ++nt) {
                int c = wave * 64 + nt * 16 + l16;
                uP[row * 512 + (((c >> 3) ^ rho) << 3) + (c & 7)] = f2bf(oacc[mt][nt][r]);
            }
        }
    }
    __syncthreads();

    // ---- out-proj: wave owns cols wave*64..+63; woT frags from L2; no barriers ----
    f32x4 pacc[4][4];
#pragma unroll
    for (int i = 0; i < 4; ++i)
#pragma unroll
        for (int j = 0; j < 4; ++j) pacc[i][j] = (f32x4){0.f, 0.f, 0.f, 0.f};
#pragma unroll 4
    for (int kc = 0; kc < 16; ++kc) {
        bhalf8 af[4], bw[4];
#pragma unroll
        for (int mt = 0; mt < 4; ++mt)
            af[mt] = *(const bhalf8*)(uP + (mt * 16 + l16) * 512 +
                                      (((kc * 4 + g) ^ (l16 & 7)) << 3));
#pragma unroll
        for (int nt = 0; nt < 4; ++nt)
            bw[nt] = *(const bhalf8*)(woT + (size_t)(wave * 64 + nt * 16 + l16) * HID +
                                      kc * 32 + g * 8);
#pragma unroll
        for (int mt = 0; mt < 4; ++mt)
#pragma unroll
            for (int nt = 0; nt < 4; ++nt)
                pacc[mt][nt] = __builtin_amdgcn_mfma_f32_16x16x32_bf16(
                    af[mt], bw[nt], pacc[mt][nt], 0, 0, 0);
    }

    // ---- + b_out + residual; LN partials ----
#pragma unroll
    for (int mt = 0; mt < 4; ++mt) {
#pragma unroll
        for (int r = 0; r < 4; ++r) {
            int row = mt * 16 + g * 4 + r;
            float rs = 0.f, rq = 0.f;
#pragma unroll
            for (int nt = 0; nt < 4; ++nt) {
                int col = wave * 64 + nt * 16 + l16;
                float v = pacc[mt][nt][r] + b_out[col] +
                          h[(size_t)(rowbase + row) * HID + col];
                pacc[mt][nt][r] = v;
                rs += v;
                rq = fmaf(v, v, rq);
            }
#pragma unroll
            for (int off = 1; off < 16; off <<= 1) {
                rs += __shfl_xor(rs, off, 64);
                rq += __shfl_xor(rq, off, 64);
            }
            if (l16 == 0) {
                red[row * 16 + wave * 2 + 0] = rs;
                red[row * 16 + wave * 2 + 1] = rq;
            }
        }
    }
    __syncthreads();
    if (t < 64) {
        float s = 0.f, q = 0.f;
#pragma unroll
        for (int w = 0; w < 8; ++w) {
            s += red[t * 16 + w * 2 + 0];
            q += red[t * 16 + w * 2 + 1];
        }
        float mean = s * (1.0f / 512.0f);
        float var = q * (1.0f / 512.0f) - mean * mean;
        mr[t * 2 + 0] = mean;
        mr[t * 2 + 1] = rsqrtf(var + 1e-5f);
    }
    __syncthreads();
#pragma unroll
    for (int mt = 0; mt < 4; ++mt) {
#pragma unroll
        for (int r = 0; r < 4; ++r) {
            int row = mt * 16 + g * 4 + r;
            float mean = mr[row * 2 + 0], rstd = mr[row * 2 + 1];
#pragma unroll
            for (int nt = 0; nt < 4; ++nt) {
                int col = wave * 64 + nt * 16 + l16;
                out[(size_t)(rowbase + row) * HID + col] =
                    fmaf((pacc[mt][nt][r] - mean) * rstd, gamma[col], beta[col]);
            }
        }
    }
}

extern "C" void kernel_launch(void* const* d_in, const int* in_sizes, int n_in,
                              void* d_out, int out_size, void* d_ws, size_t ws_size,
                              hipStream_t stream) {
    (void)in_sizes; (void)n_in; (void)out_size; (void)ws_size;
    const float* h       = (const float*)d_in[0];
    const float* pos     = (const float*)d_in[1];
    // d_in[2] = batch (unused: equal-size contiguous molecules)
    const float* centers = (const float*)d_in[3];
    const float* w_rbf   = (const float*)d_in[4];
    const float* b_rbf   = (const float*)d_in[5];
    const float* w_qkv   = (const float*)d_in[6];
    const float* b_qkv   = (const float*)d_in[7];
    const float* w_out   = (const float*)d_in[8];
    const float* b_out   = (const float*)d_in[9];
    const float* gamma   = (const float*)d_in[10];
    const float* beta    = (const float*)d_in[11];
    float* out = (float*)d_out;

    char* ws = (char*)d_ws;
    short* wqT  = (short*)ws;                      // [1536][512] bf16 = 1.5 MB (swizzled)
    short* woT  = (short*)(ws + 1572864);          // [512][512]  bf16 = 0.5 MB (plain)
    float* tbl  = (float*)(ws + 2097152);          // [8][512]    f32  = 16 KB
    short* hbf  = (short*)(ws + 2162688);          // [32768][512] bf16 = 32 MB (half, swizzled)
    short* qkvb = (short*)(ws + 35717120);         // [512][3][8][64][64] bf16 = 50.3 MB (half)

    k_prep_w<<<256, 256, 0, stream>>>(w_qkv, w_out, wqT, woT);
    k_prep_tbl<<<16, 256, 0, stream>>>(centers, w_rbf, b_rbf, tbl);
    for (int half = 0; half < 2; ++half) {
        int molbase = half * 512;
        k_prep_h<<<8192, 256, 0, stream>>>(h, hbf, molbase);
        k_qkv<<<1536, 512, 0, stream>>>(hbf, b_qkv, wqT, qkvb);
        k_fused<<<512, 512, 0, stream>>>(qkvb, pos, tbl, h, woT, b_out,
                                         gamma, beta, out, molbase);
    }
}

// Round 12
// 390.359 us; speedup vs baseline: 1.1799x; 1.1799x over previous
//
#include <hip/hip_runtime.h>
#include <hip/hip_bf16.h>

// PointSelfAttention R12 (= R9 + k_fused latency work: bf16 residual, V-frag prefetch,
//   woT reg double-buffer, residual prefetch; dataflow/LDS identical to R9):
//   k_prep_w  : w_qkv -> bf16 [col][K] PRE-SWIZZLED; w_out -> bf16 [col][K] plain
//   k_prep_tbl: per-head RBF bias table (512 entries)
//   k_prep_h  : h fp32 -> bf16, pre-swizzled, per half
//   k_qkv     : m97-style GEMM 128x256 tile BK=64, global_load_lds, 48KB LDS
//   k_fused   : per molecule (8 waves = 8 heads): dist-cache, QK^T+bias(lerp),
//               softmax, PV, out-proj, residual+LN.

#define HID 512
#define TBL 512
#define DMAX 12.0f

typedef __attribute__((ext_vector_type(4))) float f32x4;
typedef __attribute__((ext_vector_type(8))) short bhalf8;

__device__ __forceinline__ short f2bf(float f) {
    union { float f; unsigned u; } x; x.f = f;
    unsigned u = x.u;
    unsigned r = (u + 0x7FFFu + ((u >> 16) & 1u)) >> 16;  // RNE
    return (short)r;
}

__device__ __forceinline__ float bf2f(unsigned short s) {
    union { unsigned u; float f; } x; x.u = ((unsigned)s) << 16;
    return x.f;
}

__device__ __forceinline__ void gld_lds16(const void* g, void* l) {
    __builtin_amdgcn_global_load_lds((const __attribute__((address_space(1))) void*)g,
                                     (__attribute__((address_space(3))) void*)l, 16, 0, 0);
}

// ---- prep: transpose weights to bf16 [cols][K]; wqT pre-swizzled ----
__global__ __launch_bounds__(256) void k_prep_w(const float* __restrict__ w_qkv,
                                                const float* __restrict__ w_out,
                                                short* __restrict__ wqT,
                                                short* __restrict__ woT) {
    __shared__ short tile[64][68];
    const int t = threadIdx.x;
    int bt = blockIdx.x;
    const float* src; short* dst; int sld, tk, tc, swz;
    if (bt < 192) { src = w_qkv; dst = wqT; sld = 1536; tk = bt & 7; tc = bt >> 3; swz = 1; }
    else { int b2 = bt - 192; src = w_out; dst = woT; sld = 512; tk = b2 & 7; tc = b2 >> 3; swz = 0; }
#pragma unroll
    for (int p = 0; p < 4; ++p) {
        int s = t + 256 * p;
        int r = s >> 4, sg = s & 15;
        const float4 v = *(const float4*)(src + (tk * 64 + r) * sld + tc * 64 + sg * 4);
        tile[r][sg * 4 + 0] = f2bf(v.x);
        tile[r][sg * 4 + 1] = f2bf(v.y);
        tile[r][sg * 4 + 2] = f2bf(v.z);
        tile[r][sg * 4 + 3] = f2bf(v.w);
    }
    __syncthreads();
#pragma unroll
    for (int p = 0; p < 16; ++p) {
        int o = t + 256 * p;
        int c = o >> 6, k = o & 63;
        int kk = swz ? (k ^ ((c & 7) << 3)) : k;
        dst[(tc * 64 + c) * 512 + tk * 64 + kk] = tile[k][c];
    }
}

// ---- prep: per-head bias(d) table [8][512] ----
__global__ __launch_bounds__(256) void k_prep_tbl(const float* __restrict__ centers,
                                                  const float* __restrict__ w_rbf,
                                                  const float* __restrict__ b_rbf,
                                                  float* __restrict__ tbl) {
    int idx = blockIdx.x * 256 + threadIdx.x;   // 8 heads * 512
    int hh = idx >> 9, i = idx & (TBL - 1);
    float d = (float)i * (DMAX / (float)(TBL - 1));
    float s = b_rbf[hh];
    const float invw = 1.0f / 0.0625f;          // width = (8/32)^2
#pragma unroll 4
    for (int r = 0; r < 32; ++r) {
        float tt = d - centers[r];
        s += w_rbf[r * 8 + hh] * expf(-(tt * tt) * invw);
    }
    tbl[idx] = s;
}

// ---- prep: h (fp32) -> bf16 pre-swizzled, one half (32768 rows) ----
__global__ __launch_bounds__(256) void k_prep_h(const float* __restrict__ h,
                                                short* __restrict__ hbf,
                                                int molbase) {
    size_t i = ((size_t)blockIdx.x * 256 + threadIdx.x) * 8;   // short idx within half
    const float* src = h + (size_t)molbase * 64 * HID + i;
    float4 a = *(const float4*)src;
    float4 b = *(const float4*)(src + 4);
    short s8[8];
    s8[0] = f2bf(a.x); s8[1] = f2bf(a.y); s8[2] = f2bf(a.z); s8[3] = f2bf(a.w);
    s8[4] = f2bf(b.x); s8[5] = f2bf(b.y); s8[6] = f2bf(b.z); s8[7] = f2bf(b.w);
    int row = (int)(i >> 9);
    size_t o = i ^ (size_t)((row & 7) << 3);   // swizzle 16B slots within 64-short chunk
    *(int4*)(hbf + o) = *(int4*)s8;
}

// ---- QKV GEMM (m97-style): 128x256 tile, BK=64, global_load_lds, 1 buffer ----
__global__ __launch_bounds__(512) void k_qkv(const short* __restrict__ hbf,
                                             const float* __restrict__ b_qkv,
                                             const short* __restrict__ wqT,
                                             short* __restrict__ qkvb) {
    __shared__ __align__(16) short As[128 * 64];   // 16 KB
    __shared__ __align__(16) short Bs[256 * 64];   // 32 KB
    const int t = threadIdx.x;
    const int lane = t & 63, wave = t >> 6;
    const int l16 = lane & 15, g = lane >> 4;
    const int wrow = wave >> 2, wcol = wave & 3;   // 2 x 4 wave grid

    int wg = blockIdx.x;                           // 1536 wgs; XCD swizzle
    wg = (wg & 7) * 192 + (wg >> 3);
    const int bx = wg & 255, by = wg >> 8;
    const int R0l = bx * 128;
    const int C0 = by * 256;

    f32x4 acc[4][4];
#pragma unroll
    for (int i = 0; i < 4; ++i)
#pragma unroll
        for (int j = 0; j < 4; ++j) acc[i][j] = (f32x4){0.f, 0.f, 0.f, 0.f};

    const int lrow = lane >> 3, lslot = lane & 7;
    const int axor = (l16 & 7) << 3;

    for (int kc = 0; kc < 8; ++kc) {
        const int kb = kc * 64;
#pragma unroll
        for (int j = 0; j < 2; ++j) {
            int row = wave * 16 + j * 8 + lrow;
            gld_lds16(hbf + (size_t)(R0l + row) * HID + kb + lslot * 8,
                      (char*)As + wave * 2048 + j * 1024 + lane * 16);
        }
#pragma unroll
        for (int j = 0; j < 4; ++j) {
            int row = wave * 32 + j * 8 + lrow;
            gld_lds16(wqT + (size_t)(C0 + row) * HID + kb + lslot * 8,
                      (char*)Bs + wave * 4096 + j * 1024 + lane * 16);
        }
        __syncthreads();
#pragma unroll
        for (int kk = 0; kk < 2; ++kk) {
            const int cs = (kk * 32 + g * 8) ^ axor;
            bhalf8 af[4], bf[4];
#pragma unroll
            for (int mt = 0; mt < 4; ++mt)
                af[mt] = *(const bhalf8*)(&As[(wrow * 64 + mt * 16 + l16) * 64 + cs]);
#pragma unroll
            for (int nt = 0; nt < 4; ++nt)
                bf[nt] = *(const bhalf8*)(&Bs[(wcol * 64 + nt * 16 + l16) * 64 + cs]);
#pragma unroll
            for (int mt = 0; mt < 4; ++mt)
#pragma unroll
                for (int nt = 0; nt < 4; ++nt)
                    acc[mt][nt] = __builtin_amdgcn_mfma_f32_16x16x32_bf16(
                        af[mt], bf[nt], acc[mt][nt], 0, 0, 0);
        }
        __syncthreads();
    }

    const int sec = C0 >> 9;
    const float mul = (sec == 0) ? 0.125f : 1.0f;
#pragma unroll
    for (int nt = 0; nt < 4; ++nt) {
        int c = C0 + wcol * 64 + nt * 16 + l16;
        float bv = b_qkv[c];
        int head = (c >> 6) & 7, d = c & 63;
#pragma unroll
        for (int mt = 0; mt < 4; ++mt) {
            int rowl = R0l + wrow * 64 + mt * 16 + g * 4;
            int mol_local = rowl >> 6;
            int rloc = rowl & 63;
            short* panel = qkvb + (size_t)((mol_local * 3 + sec) * 8 + head) * 4096;
            if (sec == 2) {
                short4 s4;
                s4.x = f2bf(acc[mt][nt][0] + bv);
                s4.y = f2bf(acc[mt][nt][1] + bv);
                s4.z = f2bf(acc[mt][nt][2] + bv);
                s4.w = f2bf(acc[mt][nt][3] + bv);
                *(short4*)(panel + d * 64 + rloc) = s4;
            } else {
#pragma unroll
                for (int r = 0; r < 4; ++r)
                    panel[(rloc + r) * 64 + d] = f2bf((acc[mt][nt][r] + bv) * mul);
            }
        }
    }
}

// ---- fused attention + out-proj + residual + LayerNorm; 1 block = 1 molecule ----
__global__ __launch_bounds__(512) void k_fused(const short* __restrict__ qkvb,
                                               const float* __restrict__ pos,
                                               const float* __restrict__ tbl,
                                               const short* __restrict__ hbfr,
                                               const short* __restrict__ woT,
                                               const float* __restrict__ b_out,
                                               const float* __restrict__ gamma,
                                               const float* __restrict__ beta,
                                               float* __restrict__ out,
                                               int molbase) {
    __shared__ __align__(16) short uP[8 * 4096];   // per-wave P[64][64] -> agg[64][512]
    __shared__ float s_tbl[8 * 516];               // 16.5 KB bias tables
    __shared__ float s_dc[64 * 66];                // 16.9 KB dist-cache u[row][col]
    __shared__ float s_px[64], s_py[64], s_pz[64];
    __shared__ float red[64 * 16];
    __shared__ float mr[64 * 2];

    const int t = threadIdx.x;
    const int wave = t >> 6, lane = t & 63;
    const int l16 = lane & 15, g = lane >> 4;
    const int mol_local = blockIdx.x;
    const int rowbase = (molbase + mol_local) * 64;
    const float tscale = (float)(TBL - 1) / DMAX;

    for (int i = t; i < 8 * TBL; i += 512)
        s_tbl[(i >> 9) * 516 + (i & (TBL - 1))] = tbl[i];
    if (t < 64) {
        s_px[t] = pos[(rowbase + t) * 3 + 0];
        s_py[t] = pos[(rowbase + t) * 3 + 1];
        s_pz[t] = pos[(rowbase + t) * 3 + 2];
    }
    __syncthreads();

    // shared distance cache: u = min(dist,DMAX)*tscale, once per molecule
    {
        int row = t >> 3, c0 = (t & 7) * 8;
        float rx = s_px[row], ry = s_py[row], rz = s_pz[row];
#pragma unroll
        for (int j = 0; j < 8; ++j) {
            int col = c0 + j;
            float dx = rx - s_px[col], dy = ry - s_py[col], dz = rz - s_pz[col];
            float dd = fmaf(dx, dx, fmaf(dy, dy, dz * dz));
            float dist = sqrtf(fmaxf(dd, 1e-12f));
            s_dc[row * 66 + col] = fminf(dist, DMAX) * tscale;
        }
    }
    __syncthreads();

    const short* qp = qkvb + ((size_t)(mol_local * 3 + 0) * 8 + wave) * 4096;
    const short* kp = qkvb + ((size_t)(mol_local * 3 + 1) * 8 + wave) * 4096;
    const short* vt = qkvb + ((size_t)(mol_local * 3 + 2) * 8 + wave) * 4096;  // [d][key]

    // ---- S = q_scaled . k^T (wave owns full 64x64 of its head) ----
    f32x4 sacc[4][4];
#pragma unroll
    for (int i = 0; i < 4; ++i)
#pragma unroll
        for (int j = 0; j < 4; ++j) sacc[i][j] = (f32x4){0.f, 0.f, 0.f, 0.f};
#pragma unroll
    for (int kk = 0; kk < 2; ++kk) {
        bhalf8 qa[4], kb[4];
#pragma unroll
        for (int mt = 0; mt < 4; ++mt)
            qa[mt] = *(const bhalf8*)(qp + (mt * 16 + l16) * 64 + kk * 32 + g * 8);
#pragma unroll
        for (int nt = 0; nt < 4; ++nt)
            kb[nt] = *(const bhalf8*)(kp + (nt * 16 + l16) * 64 + kk * 32 + g * 8);
#pragma unroll
        for (int mt = 0; mt < 4; ++mt)
#pragma unroll
            for (int nt = 0; nt < 4; ++nt)
                sacc[mt][nt] = __builtin_amdgcn_mfma_f32_16x16x32_bf16(
                    qa[mt], kb[nt], sacc[mt][nt], 0, 0, 0);
    }

    // ---- V-frag prefetch (T14): issue now, consume in PV after softmax ----
    bhalf8 vb[2][4];
#pragma unroll
    for (int kk = 0; kk < 2; ++kk)
#pragma unroll
        for (int nt = 0; nt < 4; ++nt)
            vb[kk][nt] = *(const bhalf8*)(vt + (nt * 16 + l16) * 64 + kk * 32 + g * 8);

    // ---- + RBF bias via shared u + per-head table lerp ----
    const float* T = s_tbl + wave * 516;
#pragma unroll
    for (int nt = 0; nt < 4; ++nt) {
        int col = nt * 16 + l16;
#pragma unroll
        for (int mt = 0; mt < 4; ++mt) {
#pragma unroll
            for (int r = 0; r < 4; ++r) {
                int row = mt * 16 + g * 4 + r;
                float u = s_dc[row * 66 + col];
                int i = (int)u; if (i > TBL - 2) i = TBL - 2;
                float fr = u - (float)i;
                float t0 = T[i];
                sacc[mt][nt][r] += fmaf(fr, T[i + 1] - t0, t0);
            }
        }
    }

    // ---- softmax rows + P (XOR-swizzled 16-B groups) ----
    float inv[4][4];
    short* Pw = uP + wave * 4096;
#pragma unroll
    for (int mt = 0; mt < 4; ++mt) {
#pragma unroll
        for (int r = 0; r < 4; ++r) {
            float m = fmaxf(fmaxf(sacc[mt][0][r], sacc[mt][1][r]),
                            fmaxf(sacc[mt][2][r], sacc[mt][3][r]));
#pragma unroll
            for (int off = 1; off < 16; off <<= 1) m = fmaxf(m, __shfl_xor(m, off, 64));
            float e[4], ssum = 0.f;
#pragma unroll
            for (int nt = 0; nt < 4; ++nt) { e[nt] = __expf(sacc[mt][nt][r] - m); ssum += e[nt]; }
#pragma unroll
            for (int off = 1; off < 16; off <<= 1) ssum += __shfl_xor(ssum, off, 64);
            inv[mt][r] = 1.0f / ssum;
            int row = mt * 16 + g * 4 + r;
            int rho = row & 7;
#pragma unroll
            for (int nt = 0; nt < 4; ++nt) {
                int c = nt * 16 + l16;
                Pw[row * 64 + (((c >> 3) ^ rho) << 3) + (c & 7)] = f2bf(e[nt]);
            }
        }
    }

    // ---- PV: agg_head = P @ V  (V frags already in registers) ----
    f32x4 oacc[4][4];
#pragma unroll
    for (int i = 0; i < 4; ++i)
#pragma unroll
        for (int j = 0; j < 4; ++j) oacc[i][j] = (f32x4){0.f, 0.f, 0.f, 0.f};
#pragma unroll
    for (int kk = 0; kk < 2; ++kk) {
        bhalf8 pa[4];
#pragma unroll
        for (int mt = 0; mt < 4; ++mt)
            pa[mt] = *(const bhalf8*)(Pw + (mt * 16 + l16) * 64 +
                                      (((kk * 4 + g) ^ (l16 & 7)) << 3));
#pragma unroll
        for (int mt = 0; mt < 4; ++mt)
#pragma unroll
            for (int nt = 0; nt < 4; ++nt)
                oacc[mt][nt] = __builtin_amdgcn_mfma_f32_16x16x32_bf16(
                    pa[mt], vb[kk][nt], oacc[mt][nt], 0, 0, 0);
    }
#pragma unroll
    for (int mt = 0; mt < 4; ++mt)
#pragma unroll
        for (int nt = 0; nt < 4; ++nt)
#pragma unroll
            for (int r = 0; r < 4; ++r) oacc[mt][nt][r] *= inv[mt][r];

    __syncthreads();   // all waves done reading P; uP becomes agg[64][512]

#pragma unroll
    for (int mt = 0; mt < 4; ++mt) {
#pragma unroll
        for (int r = 0; r < 4; ++r) {
            int row = mt * 16 + g * 4 + r;
            int rho = row & 7;
#pragma unroll
            for (int nt = 0; nt < 4; ++nt) {
                int c = wave * 64 + nt * 16 + l16;
                uP[row * 512 + (((c >> 3) ^ rho) << 3) + (c & 7)] = f2bf(oacc[mt][nt][r]);
            }
        }
    }
    __syncthreads();

    // ---- residual prefetch (bf16 from swizzled hbf): drains under out-proj MFMA ----
    unsigned short hres[4][4][4];                  // [mt][r][nt]
#pragma unroll
    for (int mt = 0; mt < 4; ++mt)
#pragma unroll
        for (int r = 0; r < 4; ++r) {
            int row = mt * 16 + g * 4 + r;
            size_t rbase = (size_t)(mol_local * 64 + row) * HID;
            int sw = (row & 7) << 3;
#pragma unroll
            for (int nt = 0; nt < 4; ++nt) {
                int col = wave * 64 + nt * 16 + l16;
                hres[mt][r][nt] = *(const unsigned short*)(hbfr + rbase + (col ^ sw));
            }
        }

    // ---- out-proj: wave owns cols wave*64..+63; woT frags reg-double-buffered ----
    f32x4 pacc[4][4];
#pragma unroll
    for (int i = 0; i < 4; ++i)
#pragma unroll
        for (int j = 0; j < 4; ++j) pacc[i][j] = (f32x4){0.f, 0.f, 0.f, 0.f};
    bhalf8 bwc[4], bwn[4];
#pragma unroll
    for (int nt = 0; nt < 4; ++nt)
        bwc[nt] = *(const bhalf8*)(woT + (size_t)(wave * 64 + nt * 16 + l16) * HID + g * 8);
#pragma unroll
    for (int kc = 0; kc < 16; ++kc) {
        if (kc < 15) {
#pragma unroll
            for (int nt = 0; nt < 4; ++nt)
                bwn[nt] = *(const bhalf8*)(woT + (size_t)(wave * 64 + nt * 16 + l16) * HID +
                                           (kc + 1) * 32 + g * 8);
        }
        bhalf8 af[4];
#pragma unroll
        for (int mt = 0; mt < 4; ++mt)
            af[mt] = *(const bhalf8*)(uP + (mt * 16 + l16) * 512 +
                                      (((kc * 4 + g) ^ (l16 & 7)) << 3));
#pragma unroll
        for (int mt = 0; mt < 4; ++mt)
#pragma unroll
            for (int nt = 0; nt < 4; ++nt)
                pacc[mt][nt] = __builtin_amdgcn_mfma_f32_16x16x32_bf16(
                    af[mt], bwc[nt], pacc[mt][nt], 0, 0, 0);
#pragma unroll
        for (int nt = 0; nt < 4; ++nt) bwc[nt] = bwn[nt];
    }

    // ---- + b_out + residual; LN partials ----
#pragma unroll
    for (int mt = 0; mt < 4; ++mt) {
#pragma unroll
        for (int r = 0; r < 4; ++r) {
            int row = mt * 16 + g * 4 + r;
            float rs = 0.f, rq = 0.f;
#pragma unroll
            for (int nt = 0; nt < 4; ++nt) {
                int col = wave * 64 + nt * 16 + l16;
                float v = pacc[mt][nt][r] + b_out[col] + bf2f(hres[mt][r][nt]);
                pacc[mt][nt][r] = v;
                rs += v;
                rq = fmaf(v, v, rq);
            }
#pragma unroll
            for (int off = 1; off < 16; off <<= 1) {
                rs += __shfl_xor(rs, off, 64);
                rq += __shfl_xor(rq, off, 64);
            }
            if (l16 == 0) {
                red[row * 16 + wave * 2 + 0] = rs;
                red[row * 16 + wave * 2 + 1] = rq;
            }
        }
    }
    __syncthreads();
    if (t < 64) {
        float s = 0.f, q = 0.f;
#pragma unroll
        for (int w = 0; w < 8; ++w) {
            s += red[t * 16 + w * 2 + 0];
            q += red[t * 16 + w * 2 + 1];
        }
        float mean = s * (1.0f / 512.0f);
        float var = q * (1.0f / 512.0f) - mean * mean;
        mr[t * 2 + 0] = mean;
        mr[t * 2 + 1] = rsqrtf(var + 1e-5f);
    }
    __syncthreads();
#pragma unroll
    for (int mt = 0; mt < 4; ++mt) {
#pragma unroll
        for (int r = 0; r < 4; ++r) {
            int row = mt * 16 + g * 4 + r;
            float mean = mr[row * 2 + 0], rstd = mr[row * 2 + 1];
#pragma unroll
            for (int nt = 0; nt < 4; ++nt) {
                int col = wave * 64 + nt * 16 + l16;
                out[(size_t)(rowbase + row) * HID + col] =
                    fmaf((pacc[mt][nt][r] - mean) * rstd, gamma[col], beta[col]);
            }
        }
    }
}

extern "C" void kernel_launch(void* const* d_in, const int* in_sizes, int n_in,
                              void* d_out, int out_size, void* d_ws, size_t ws_size,
                              hipStream_t stream) {
    (void)in_sizes; (void)n_in; (void)out_size; (void)ws_size;
    const float* h       = (const float*)d_in[0];
    const float* pos     = (const float*)d_in[1];
    // d_in[2] = batch (unused: equal-size contiguous molecules)
    const float* centers = (const float*)d_in[3];
    const float* w_rbf   = (const float*)d_in[4];
    const float* b_rbf   = (const float*)d_in[5];
    const float* w_qkv   = (const float*)d_in[6];
    const float* b_qkv   = (const float*)d_in[7];
    const float* w_out   = (const float*)d_in[8];
    const float* b_out   = (const float*)d_in[9];
    const float* gamma   = (const float*)d_in[10];
    const float* beta    = (const float*)d_in[11];
    float* out = (float*)d_out;

    char* ws = (char*)d_ws;
    short* wqT  = (short*)ws;                      // [1536][512] bf16 = 1.5 MB (swizzled)
    short* woT  = (short*)(ws + 1572864);          // [512][512]  bf16 = 0.5 MB (plain)
    float* tbl  = (float*)(ws + 2097152);          // [8][512]    f32  = 16 KB
    short* hbf  = (short*)(ws + 2162688);          // [32768][512] bf16 = 32 MB (half, swizzled)
    short* qkvb = (short*)(ws + 35717120);         // [512][3][8][64][64] bf16 = 50.3 MB (half)

    k_prep_w<<<256, 256, 0, stream>>>(w_qkv, w_out, wqT, woT);
    k_prep_tbl<<<16, 256, 0, stream>>>(centers, w_rbf, b_rbf, tbl);
    for (int half = 0; half < 2; ++half) {
        int molbase = half * 512;
        k_prep_h<<<8192, 256, 0, stream>>>(h, hbf, molbase);
        k_qkv<<<1536, 512, 0, stream>>>(hbf, b_qkv, wqT, qkvb);
        k_fused<<<512, 512, 0, stream>>>(qkvb, pos, tbl, hbf, woT, b_out,
                                         gamma, beta, out, molbase);
    }
}